// Round 2
// baseline (313.910 us; speedup 1.0000x reference)
//
#include <hip/hip_runtime.h>

// VQ-VAE quantization: z [16384 x 512] f32, codebook [8192 x 512] f32.
// out = concat(z_st [16384*512] f32, vq_loss [1] f32).
//
// R4: MX-fp8 (e4m3, K=128 scaled MFMA, scale=1.0) scores GEMM — 2x MFMA
// rate + half staging vs bf16. Codebook pre-scaled by 2^13 (exact) into
// fp8 range; argmin on d' = 8192*||e||^2 - 2*z.(8192e). Argmin flips are
// bounded by 2/8192 = 2.441e-4 per output element (== current absmax).
// Packed (dist|idx) u32 argmin epilogue: monotone uint transform, low 13
// bits = code index -> reduce is shfl+umin, ties pick lowest index free.
// reduce_cand fused into gather_out; convert_z+convert_cb fused. 3 launches.
// R5: fix — cvt_pk_fp8_f32 'hi' operand must be an ICE -> template param.

#define M_ROWS 16384
#define K_CODES 8192
#define DIM 512
#define BM 128
#define BN 128
#define BK 128                 // fp8 bytes per K-step (one 16x16x128 MFMA)
#define NT (K_CODES / BN)      // 64 candidate tiles per row
#define OUT0_SIZE (M_ROWS * DIM)
#define GB_BLOCKS 1024

typedef int   i32x8 __attribute__((ext_vector_type(8)));
typedef float f32x4 __attribute__((ext_vector_type(4)));

template <bool HI>
__device__ __forceinline__ int pk8(float a, float b, int old) {
    return __builtin_amdgcn_cvt_pk_fp8_f32(a, b, old, HI);
}

// ---- kernel 1: fused converts ------------------------------------------
// blocks [0, 2048): codebook -> fp8(8192*e) + f32 norms (8192*||e||^2),
//                   one wave per row. Also zeroes the loss slot.
// blocks [2048, 6144): z -> fp8, 8 elems/thread.
__global__ __launch_bounds__(256) void convert_all(
    const float* __restrict__ z, const float* __restrict__ cb,
    unsigned char* __restrict__ z8, unsigned char* __restrict__ cb8,
    float* __restrict__ enorm, float* __restrict__ lossSlot)
{
    const int tid = threadIdx.x;
    if (blockIdx.x < K_CODES / 4) {
        const int w = tid >> 6, lane = tid & 63;
        const int row = blockIdx.x * 4 + w;
        const float* src = cb + (size_t)row * DIM + lane * 8;
        float4 a = *(const float4*)(src);
        float4 b = *(const float4*)(src + 4);
        float ns = a.x * a.x + a.y * a.y + a.z * a.z + a.w * a.w
                 + b.x * b.x + b.y * b.y + b.z * b.z + b.w * b.w;
        const float S = 8192.0f;                 // exact power of 2
        int lo = 0, hi = 0;
        lo = pk8<false>(a.x * S, a.y * S, lo); lo = pk8<true>(a.z * S, a.w * S, lo);
        hi = pk8<false>(b.x * S, b.y * S, hi); hi = pk8<true>(b.z * S, b.w * S, hi);
        *(int2*)(cb8 + (size_t)row * DIM + lane * 8) = make_int2(lo, hi);
        for (int m = 32; m; m >>= 1) ns += __shfl_down(ns, m, 64);
        if (lane == 0) enorm[row] = S * ns;      // 8192 * ||e||^2 (f32-exact norm)
        if (blockIdx.x == 0 && tid == 0) *lossSlot = 0.f;  // k3 accumulates
    } else {
        size_t i = ((size_t)(blockIdx.x - K_CODES / 4) * 256 + tid) * 8;
        float4 a = *(const float4*)(z + i);
        float4 b = *(const float4*)(z + i + 4);
        int lo = 0, hi = 0;
        lo = pk8<false>(a.x, a.y, lo); lo = pk8<true>(a.z, a.w, lo);
        hi = pk8<false>(b.x, b.y, hi); hi = pk8<true>(b.z, b.w, hi);
        *(int2*)(z8 + i) = make_int2(lo, hi);
    }
}

// ---- kernel 2: MX-fp8 MFMA GEMM + packed-argmin epilogue ---------------
__global__ __launch_bounds__(256, 2) void gemm_argmin(
    const unsigned char* __restrict__ z8, const unsigned char* __restrict__ cb8,
    const float* __restrict__ enorm, unsigned int* __restrict__ candV)
{
    __shared__ alignas(16) unsigned char As[BM * BK];   // 16 KB
    __shared__ alignas(16) unsigned char Bs[BN * BK];   // 16 KB
    __shared__ float Es[BN];
    __shared__ unsigned int cU[BM][2];

    const int tid = threadIdx.x;
    const int lane = tid & 63;
    const int w = tid >> 6;
    const int ktile = blockIdx.x;
    const int mtile = blockIdx.y;
    const int mbase = mtile * BM;
    const int nbase = ktile * BN;

    if (tid < BN) Es[tid] = enorm[nbase + tid];

    f32x4 acc[16];
#pragma unroll
    for (int i = 0; i < 16; ++i) acc[i] = (f32x4){0.f, 0.f, 0.f, 0.f};

    const int rA = lane >> 3;                 // row within 8-row chunk
    const int jG = ((lane & 7) ^ rA) * 16;    // pre-swizzled global 16B chunk
    const int quad = lane >> 4;
    const int l15 = lane & 15;
    const int sw = l15 & 7;                   // read-side xor = row&7
    const int rw = (w >> 1) * 64;             // wave row quadrant
    const int cw = (w & 1) * 64;              // wave col quadrant

    for (int dt = 0; dt < DIM; dt += BK) {
#pragma unroll
        for (int i = 0; i < 4; ++i) {
            int c = w * 4 + i;                // 1KB chunk id (0..15): rows c*8..c*8+7
            int row = c * 8 + rA;
            const unsigned char* ga = z8 + (size_t)(mbase + row) * DIM + dt + jG;
            const unsigned char* gb = cb8 + (size_t)(nbase + row) * DIM + dt + jG;
            unsigned char* la = As + c * 1024 + lane * 16;
            unsigned char* lb = Bs + c * 1024 + lane * 16;
            __builtin_amdgcn_global_load_lds((const __attribute__((address_space(1))) void*)ga,
                                             (__attribute__((address_space(3))) void*)la, 16, 0, 0);
            __builtin_amdgcn_global_load_lds((const __attribute__((address_space(1))) void*)gb,
                                             (__attribute__((address_space(3))) void*)lb, 16, 0, 0);
        }
        __syncthreads();
        // lane holds K bytes [quad*32, quad*32+32): chunks 2q, 2q+1 (swizzled).
        // Any within-lane k-permutation cancels (A and B use identical maps).
        i32x8 af[4], bfr[4];
#pragma unroll
        for (int rf = 0; rf < 4; ++rf) {
            const unsigned char* pa = As + (rw + rf * 16 + l15) * BK;
            int4 lo = *(const int4*)(pa + ((((quad << 1) | 0) ^ sw) * 16));
            int4 hi = *(const int4*)(pa + ((((quad << 1) | 1) ^ sw) * 16));
            af[rf] = (i32x8){lo.x, lo.y, lo.z, lo.w, hi.x, hi.y, hi.z, hi.w};
        }
#pragma unroll
        for (int cf = 0; cf < 4; ++cf) {
            const unsigned char* pb = Bs + (cw + cf * 16 + l15) * BK;
            int4 lo = *(const int4*)(pb + ((((quad << 1) | 0) ^ sw) * 16));
            int4 hi = *(const int4*)(pb + ((((quad << 1) | 1) ^ sw) * 16));
            bfr[cf] = (i32x8){lo.x, lo.y, lo.z, lo.w, hi.x, hi.y, hi.z, hi.w};
        }
#pragma unroll
        for (int rf = 0; rf < 4; ++rf)
#pragma unroll
            for (int cf = 0; cf < 4; ++cf)
                acc[rf * 4 + cf] = __builtin_amdgcn_mfma_scale_f32_16x16x128_f8f6f4(
                    af[rf], bfr[cf], acc[rf * 4 + cf],
                    0, 0,                      // cbsz=fp8(e4m3), blgp=fp8(e4m3)
                    0, 0x7F7F7F7F,             // opsel_a, scale_a = 1.0 (e8m0 127)
                    0, 0x7F7F7F7F);            // opsel_b, scale_b = 1.0
        __syncthreads();
    }

    // epilogue: per-row argmin over this tile's 128 cols.
    // C/D layout: col = lane&15, row = quad*4 + reg.
    // Packed key: monotone-uint(dist) with low 13 bits = global code index.
#pragma unroll
    for (int rf = 0; rf < 4; ++rf) {
#pragma unroll
        for (int r = 0; r < 4; ++r) {
            float bv = 3.4e38f; int bi = 0;
#pragma unroll
            for (int cf = 0; cf < 4; ++cf) {
                int col = cw + cf * 16 + l15;
                float dist = Es[col] - 2.0f * acc[rf * 4 + cf][r];
                if (dist < bv) { bv = dist; bi = col; }
            }
            unsigned u = __builtin_bit_cast(unsigned, bv);
            u ^= ((unsigned)(((int)u) >> 31)) | 0x80000000u;
            unsigned key = (u & 0xFFFFE000u) | (unsigned)(nbase + bi);
#pragma unroll
            for (int m = 1; m < 16; m <<= 1) {
                unsigned o = __shfl_xor(key, m, 64);
                key = o < key ? o : key;
            }
            if (l15 == 0) cU[rw + rf * 16 + quad * 4 + r][w & 1] = key;
        }
    }
    __syncthreads();
    if (tid < BM) {
        unsigned k0 = cU[tid][0], k1 = cU[tid][1];
        candV[(size_t)(mbase + tid) * NT + ktile] = k0 < k1 ? k0 : k1;
    }
}

// ---- kernel 3: fused candidate-reduce + gather + ST output + loss ------
// 4 waves/block, each wave owns a row per iter: 64-lane umin over the 64
// packed candidates -> index, then 128 float4 slots (2 per lane).
__global__ __launch_bounds__(256) void gather_out(
    const float* __restrict__ z, const float* __restrict__ cb,
    const unsigned int* __restrict__ candV, float* __restrict__ out)
{
    __shared__ float red[4];
    const int tid = threadIdx.x;
    const int w = tid >> 6, lane = tid & 63;
    float lsum = 0.f;
#pragma unroll
    for (int it = 0; it < M_ROWS / (GB_BLOCKS * 4); ++it) {
        int row = (it * GB_BLOCKS + blockIdx.x) * 4 + w;
        unsigned key = candV[(size_t)row * NT + lane];
#pragma unroll
        for (int m = 1; m < 64; m <<= 1) {
            unsigned o = __shfl_xor(key, m, 64);
            key = o < key ? o : key;
        }
        int k = (int)(key & 8191u);
#pragma unroll
        for (int j = 0; j < 2; ++j) {
            int slot = lane + j * 64;
            float4 zv = ((const float4*)(z + (size_t)row * DIM))[slot];
            float4 cv = ((const float4*)(cb + (size_t)k * DIM))[slot];
            float dx = cv.x - zv.x, dy = cv.y - zv.y;
            float dz2 = cv.z - zv.z, dw = cv.w - zv.w;
            float4 o = {zv.x + dx, zv.y + dy, zv.z + dz2, zv.w + dw};  // z + sg(zq-z)
            ((float4*)(out + (size_t)row * DIM))[slot] = o;
            lsum += dx * dx + dy * dy + dz2 * dz2 + dw * dw;
        }
    }
    for (int m = 32; m; m >>= 1) lsum += __shfl_down(lsum, m, 64);
    if (lane == 0) red[w] = lsum;
    __syncthreads();
    if (tid == 0) {
        float t = (red[0] + red[1]) + (red[2] + red[3]);
        atomicAdd(out + OUT0_SIZE, t * (1.1f / (float)OUT0_SIZE));  // vq_loss = 1.1 * mean
    }
}

extern "C" void kernel_launch(void* const* d_in, const int* in_sizes, int n_in,
                              void* d_out, int out_size, void* d_ws, size_t ws_size,
                              hipStream_t stream) {
    const float* z = (const float*)d_in[0];     // 16*1024*512
    const float* cb = (const float*)d_in[1];    // 8192*512
    float* out = (float*)d_out;                 // 8388608 + 1
    char* ws = (char*)d_ws;

    // ws layout (bytes)
    unsigned char* z8   = (unsigned char*)(ws);               //  8,388,608
    unsigned char* cb8  = (unsigned char*)(ws + 8388608);     //  4,194,304
    float* enorm        = (float*)(ws + 12582912);            //     32,768
    unsigned int* candV = (unsigned int*)(ws + 12615680);     //  4,194,304

    convert_all<<<K_CODES / 4 + M_ROWS * DIM / 2048, 256, 0, stream>>>(
        z, cb, z8, cb8, enorm, out + OUT0_SIZE);
    gemm_argmin<<<dim3(NT, M_ROWS / BM), 256, 0, stream>>>(z8, cb8, enorm, candV);
    gather_out<<<GB_BLOCKS, 256, 0, stream>>>(z, cb, candV, out);
}

// Round 3
// 270.099 us; speedup vs baseline: 1.1622x; 1.1622x over previous
//
#include <hip/hip_runtime.h>

// VQ-VAE quantization: z [16384 x 512] f32, codebook [8192 x 512] f32.
// out = concat(z_st [16384*512] f32, vq_loss [1] f32).
//
// R4: MX-fp8 (e4m3, K=128 scaled MFMA, scale=1.0) scores GEMM. Codebook
// pre-scaled by 2^13 (exact); argmin on d' = 8192*||e||^2 - 2 z.(8192e).
// Packed (dist|idx) u32 argmin epilogue; 3 launches.
// R6: fix R5's register-spill blowup (WRITE_SIZE 354MB = scratch):
//  - fragments loaded as single 32B i32x8 LDS reads (chunks c0,c0^1 are
//    one aligned 32B block; lane-local half-swap cancels between A and B)
//    -> no int4 temps, peak ~120 VGPR, no scratch.
//  - only one A fragment live at a time (B quad hoisted).
//  - candV layout transposed to [ktile][row]: gemm writes full coalesced
//    lines (was 4B-stride-256B partial-line RMW across XCDs).

#define M_ROWS 16384
#define K_CODES 8192
#define DIM 512
#define BM 128
#define BN 128
#define BK 128                 // fp8 bytes per K-step (one 16x16x128 MFMA)
#define NT (K_CODES / BN)      // 64 candidate tiles per row
#define OUT0_SIZE (M_ROWS * DIM)
#define GB_BLOCKS 1024

typedef int   i32x8 __attribute__((ext_vector_type(8)));
typedef float f32x4 __attribute__((ext_vector_type(4)));

template <bool HI>
__device__ __forceinline__ int pk8(float a, float b, int old) {
    return __builtin_amdgcn_cvt_pk_fp8_f32(a, b, old, HI);
}

// ---- kernel 1: fused converts ------------------------------------------
// blocks [0, 2048): codebook -> fp8(8192*e) + f32 norms (8192*||e||^2),
//                   one wave per row. Also zeroes the loss slot.
// blocks [2048, 6144): z -> fp8, 8 elems/thread.
__global__ __launch_bounds__(256) void convert_all(
    const float* __restrict__ z, const float* __restrict__ cb,
    unsigned char* __restrict__ z8, unsigned char* __restrict__ cb8,
    float* __restrict__ enorm, float* __restrict__ lossSlot)
{
    const int tid = threadIdx.x;
    if (blockIdx.x < K_CODES / 4) {
        const int w = tid >> 6, lane = tid & 63;
        const int row = blockIdx.x * 4 + w;
        const float* src = cb + (size_t)row * DIM + lane * 8;
        float4 a = *(const float4*)(src);
        float4 b = *(const float4*)(src + 4);
        float ns = a.x * a.x + a.y * a.y + a.z * a.z + a.w * a.w
                 + b.x * b.x + b.y * b.y + b.z * b.z + b.w * b.w;
        const float S = 8192.0f;                 // exact power of 2
        int lo = 0, hi = 0;
        lo = pk8<false>(a.x * S, a.y * S, lo); lo = pk8<true>(a.z * S, a.w * S, lo);
        hi = pk8<false>(b.x * S, b.y * S, hi); hi = pk8<true>(b.z * S, b.w * S, hi);
        *(int2*)(cb8 + (size_t)row * DIM + lane * 8) = make_int2(lo, hi);
        for (int m = 32; m; m >>= 1) ns += __shfl_down(ns, m, 64);
        if (lane == 0) enorm[row] = S * ns;      // 8192 * ||e||^2 (f32-exact norm)
        if (blockIdx.x == 0 && tid == 0) *lossSlot = 0.f;  // k3 accumulates
    } else {
        size_t i = ((size_t)(blockIdx.x - K_CODES / 4) * 256 + tid) * 8;
        float4 a = *(const float4*)(z + i);
        float4 b = *(const float4*)(z + i + 4);
        int lo = 0, hi = 0;
        lo = pk8<false>(a.x, a.y, lo); lo = pk8<true>(a.z, a.w, lo);
        hi = pk8<false>(b.x, b.y, hi); hi = pk8<true>(b.z, b.w, hi);
        *(int2*)(z8 + i) = make_int2(lo, hi);
    }
}

// ---- kernel 2: MX-fp8 MFMA GEMM + packed-argmin epilogue ---------------
__global__ __launch_bounds__(256, 2) void gemm_argmin(
    const unsigned char* __restrict__ z8, const unsigned char* __restrict__ cb8,
    const float* __restrict__ enorm, unsigned int* __restrict__ candV)
{
    __shared__ alignas(32) unsigned char As[BM * BK];   // 16 KB
    __shared__ alignas(32) unsigned char Bs[BN * BK];   // 16 KB
    __shared__ float Es[BN];
    __shared__ unsigned int cU[BM][2];

    const int tid = threadIdx.x;
    const int lane = tid & 63;
    const int w = tid >> 6;
    const int ktile = blockIdx.x;
    const int mtile = blockIdx.y;
    const int mbase = mtile * BM;
    const int nbase = ktile * BN;

    if (tid < BN) Es[tid] = enorm[nbase + tid];

    f32x4 acc[16];
#pragma unroll
    for (int i = 0; i < 16; ++i) acc[i] = (f32x4){0.f, 0.f, 0.f, 0.f};

    const int rA = lane >> 3;                 // row within 8-row chunk
    const int jG = ((lane & 7) ^ rA) * 16;    // pre-swizzled global 16B chunk
    const int quad = lane >> 4;
    const int l15 = lane & 15;
    const int sw = l15 & 7;                   // read-side xor = row&7
    const int rw = (w >> 1) * 64;             // wave row quadrant
    const int cw = (w & 1) * 64;              // wave col quadrant
    // The two 16B chunks this lane needs, c0=(2q)^sw and c1=c0^1, form one
    // aligned 32B block at ((2q)^(sw&6))*16. Half-order may swap per lane,
    // but identically for A and B -> per-lane dot product unchanged.
    const int t32 = ((quad << 1) ^ (sw & 6)) * 16;

    for (int dt = 0; dt < DIM; dt += BK) {
#pragma unroll
        for (int i = 0; i < 4; ++i) {
            int c = w * 4 + i;                // 1KB chunk id (0..15): rows c*8..c*8+7
            int row = c * 8 + rA;
            const unsigned char* ga = z8 + (size_t)(mbase + row) * DIM + dt + jG;
            const unsigned char* gb = cb8 + (size_t)(nbase + row) * DIM + dt + jG;
            unsigned char* la = As + c * 1024 + lane * 16;
            unsigned char* lb = Bs + c * 1024 + lane * 16;
            __builtin_amdgcn_global_load_lds((const __attribute__((address_space(1))) void*)ga,
                                             (__attribute__((address_space(3))) void*)la, 16, 0, 0);
            __builtin_amdgcn_global_load_lds((const __attribute__((address_space(1))) void*)gb,
                                             (__attribute__((address_space(3))) void*)lb, 16, 0, 0);
        }
        __syncthreads();
        i32x8 bfr[4];
#pragma unroll
        for (int cf = 0; cf < 4; ++cf)
            bfr[cf] = *(const i32x8*)(Bs + (cw + cf * 16 + l15) * BK + t32);
#pragma unroll
        for (int rf = 0; rf < 4; ++rf) {
            i32x8 a = *(const i32x8*)(As + (rw + rf * 16 + l15) * BK + t32);
#pragma unroll
            for (int cf = 0; cf < 4; ++cf)
                acc[rf * 4 + cf] = __builtin_amdgcn_mfma_scale_f32_16x16x128_f8f6f4(
                    a, bfr[cf], acc[rf * 4 + cf],
                    0, 0,                      // cbsz=fp8(e4m3), blgp=fp8(e4m3)
                    0, 0x7F7F7F7F,             // opsel_a, scale_a = 1.0 (e8m0 127)
                    0, 0x7F7F7F7F);            // opsel_b, scale_b = 1.0
        }
        __syncthreads();
    }

    // epilogue: per-row argmin over this tile's 128 cols.
    // C/D layout: col = lane&15, row = quad*4 + reg.
    // Packed key: monotone-uint(dist) with low 13 bits = global code index.
    float es[4];
#pragma unroll
    for (int cf = 0; cf < 4; ++cf) es[cf] = Es[cw + cf * 16 + l15];

#pragma unroll
    for (int rf = 0; rf < 4; ++rf) {
#pragma unroll
        for (int r = 0; r < 4; ++r) {
            float bv = 3.4e38f; int bi = 0;
#pragma unroll
            for (int cf = 0; cf < 4; ++cf) {
                int col = cw + cf * 16 + l15;
                float dist = fmaf(-2.0f, acc[rf * 4 + cf][r], es[cf]);
                if (dist < bv) { bv = dist; bi = col; }  // strict <: lowest col on tie
            }
            unsigned u = __builtin_bit_cast(unsigned, bv);
            u ^= ((unsigned)(((int)u) >> 31)) | 0x80000000u;
            unsigned key = (u & 0xFFFFE000u) | (unsigned)(nbase + bi);
#pragma unroll
            for (int m = 1; m < 16; m <<= 1) {
                unsigned o = __shfl_xor(key, m, 64);
                key = o < key ? o : key;
            }
            if (l15 == 0) cU[rw + rf * 16 + quad * 4 + r][w & 1] = key;
        }
    }
    __syncthreads();
    if (tid < BM) {
        unsigned k0 = cU[tid][0], k1 = cU[tid][1];
        // [ktile][row] layout: 128 consecutive ints per block = full-line writes
        candV[(size_t)ktile * M_ROWS + mbase + tid] = k0 < k1 ? k0 : k1;
    }
}

// ---- kernel 3: fused candidate-reduce + gather + ST output + loss ------
// 4 waves/block, each wave owns a row per iter: 64-lane umin over the 64
// packed candidates (lane = ktile) -> index, then 128 float4 slots.
__global__ __launch_bounds__(256) void gather_out(
    const float* __restrict__ z, const float* __restrict__ cb,
    const unsigned int* __restrict__ candV, float* __restrict__ out)
{
    __shared__ float red[4];
    const int tid = threadIdx.x;
    const int w = tid >> 6, lane = tid & 63;
    float lsum = 0.f;
#pragma unroll
    for (int it = 0; it < M_ROWS / (GB_BLOCKS * 4); ++it) {
        int row = (it * GB_BLOCKS + blockIdx.x) * 4 + w;
        unsigned key = candV[(size_t)lane * M_ROWS + row];
#pragma unroll
        for (int m = 1; m < 64; m <<= 1) {
            unsigned o = __shfl_xor(key, m, 64);
            key = o < key ? o : key;
        }
        int k = (int)(key & 8191u);
#pragma unroll
        for (int j = 0; j < 2; ++j) {
            int slot = lane + j * 64;
            float4 zv = ((const float4*)(z + (size_t)row * DIM))[slot];
            float4 cv = ((const float4*)(cb + (size_t)k * DIM))[slot];
            float dx = cv.x - zv.x, dy = cv.y - zv.y;
            float dz2 = cv.z - zv.z, dw = cv.w - zv.w;
            float4 o = {zv.x + dx, zv.y + dy, zv.z + dz2, zv.w + dw};  // z + sg(zq-z)
            ((float4*)(out + (size_t)row * DIM))[slot] = o;
            lsum += dx * dx + dy * dy + dz2 * dz2 + dw * dw;
        }
    }
    for (int m = 32; m; m >>= 1) lsum += __shfl_down(lsum, m, 64);
    if (lane == 0) red[w] = lsum;
    __syncthreads();
    if (tid == 0) {
        float t = (red[0] + red[1]) + (red[2] + red[3]);
        atomicAdd(out + OUT0_SIZE, t * (1.1f / (float)OUT0_SIZE));  // vq_loss = 1.1 * mean
    }
}

extern "C" void kernel_launch(void* const* d_in, const int* in_sizes, int n_in,
                              void* d_out, int out_size, void* d_ws, size_t ws_size,
                              hipStream_t stream) {
    const float* z = (const float*)d_in[0];     // 16*1024*512
    const float* cb = (const float*)d_in[1];    // 8192*512
    float* out = (float*)d_out;                 // 8388608 + 1
    char* ws = (char*)d_ws;

    // ws layout (bytes)
    unsigned char* z8   = (unsigned char*)(ws);               //  8,388,608
    unsigned char* cb8  = (unsigned char*)(ws + 8388608);     //  4,194,304
    float* enorm        = (float*)(ws + 12582912);            //     32,768
    unsigned int* candV = (unsigned int*)(ws + 12615680);     //  4,194,304

    convert_all<<<K_CODES / 4 + M_ROWS * DIM / 2048, 256, 0, stream>>>(
        z, cb, z8, cb8, enorm, out + OUT0_SIZE);
    gemm_argmin<<<dim3(NT, M_ROWS / BM), 256, 0, stream>>>(z8, cb8, enorm, candV);
    gather_out<<<GB_BLOCKS, 256, 0, stream>>>(z, cb, candV, out);
}

// Round 4
// 270.019 us; speedup vs baseline: 1.1626x; 1.0003x over previous
//
#include <hip/hip_runtime.h>

// VQ-VAE quantization: z [16384 x 512] f32, codebook [8192 x 512] f32.
// out = concat(z_st [16384*512] f32, vq_loss [1] f32).
//
// R4: MX-fp8 (e4m3, K=128 scaled MFMA, scale=1.0) scores GEMM. Codebook
// pre-scaled by 2^13 (exact); argmin on d' = 8192*||e||^2 - 2 z.(8192e).
// Packed (dist|idx) u32 argmin epilogue; 3 launches.
// R6: spill fix (one A frag live; candV [ktile][row] coalesced writes).
// R7: bank-conflict fix — R6's 32B-aligned fragment load dropped the low
// swizzle bit (4 chunks/quad -> 4-way conflict, 8.4M/dispatch). Back to
// full 16B XOR swizzle with two explicit b128 reads per fragment
// (chunks (2q)^sw and ((2q)^sw)^1): 8 chunks x 2 lanes per quad = free.
// B quad hoisted, A per-rf -> no spill (peak ~120 VGPR).

#define M_ROWS 16384
#define K_CODES 8192
#define DIM 512
#define BM 128
#define BN 128
#define BK 128                 // fp8 bytes per K-step (one 16x16x128 MFMA)
#define NT (K_CODES / BN)      // 64 candidate tiles per row
#define OUT0_SIZE (M_ROWS * DIM)
#define GB_BLOCKS 1024

typedef int   i32x8 __attribute__((ext_vector_type(8)));
typedef float f32x4 __attribute__((ext_vector_type(4)));

template <bool HI>
__device__ __forceinline__ int pk8(float a, float b, int old) {
    return __builtin_amdgcn_cvt_pk_fp8_f32(a, b, old, HI);
}

// ---- kernel 1: fused converts ------------------------------------------
// blocks [0, 2048): codebook -> fp8(8192*e) + f32 norms (8192*||e||^2),
//                   one wave per row. Also zeroes the loss slot.
// blocks [2048, 6144): z -> fp8, 8 elems/thread.
__global__ __launch_bounds__(256) void convert_all(
    const float* __restrict__ z, const float* __restrict__ cb,
    unsigned char* __restrict__ z8, unsigned char* __restrict__ cb8,
    float* __restrict__ enorm, float* __restrict__ lossSlot)
{
    const int tid = threadIdx.x;
    if (blockIdx.x < K_CODES / 4) {
        const int w = tid >> 6, lane = tid & 63;
        const int row = blockIdx.x * 4 + w;
        const float* src = cb + (size_t)row * DIM + lane * 8;
        float4 a = *(const float4*)(src);
        float4 b = *(const float4*)(src + 4);
        float ns = a.x * a.x + a.y * a.y + a.z * a.z + a.w * a.w
                 + b.x * b.x + b.y * b.y + b.z * b.z + b.w * b.w;
        const float S = 8192.0f;                 // exact power of 2
        int lo = 0, hi = 0;
        lo = pk8<false>(a.x * S, a.y * S, lo); lo = pk8<true>(a.z * S, a.w * S, lo);
        hi = pk8<false>(b.x * S, b.y * S, hi); hi = pk8<true>(b.z * S, b.w * S, hi);
        *(int2*)(cb8 + (size_t)row * DIM + lane * 8) = make_int2(lo, hi);
        for (int m = 32; m; m >>= 1) ns += __shfl_down(ns, m, 64);
        if (lane == 0) enorm[row] = S * ns;      // 8192 * ||e||^2 (f32-exact norm)
        if (blockIdx.x == 0 && tid == 0) *lossSlot = 0.f;  // k3 accumulates
    } else {
        size_t i = ((size_t)(blockIdx.x - K_CODES / 4) * 256 + tid) * 8;
        float4 a = *(const float4*)(z + i);
        float4 b = *(const float4*)(z + i + 4);
        int lo = 0, hi = 0;
        lo = pk8<false>(a.x, a.y, lo); lo = pk8<true>(a.z, a.w, lo);
        hi = pk8<false>(b.x, b.y, hi); hi = pk8<true>(b.z, b.w, hi);
        *(int2*)(z8 + i) = make_int2(lo, hi);
    }
}

// ---- kernel 2: MX-fp8 MFMA GEMM + packed-argmin epilogue ---------------
__global__ __launch_bounds__(256, 2) void gemm_argmin(
    const unsigned char* __restrict__ z8, const unsigned char* __restrict__ cb8,
    const float* __restrict__ enorm, unsigned int* __restrict__ candV)
{
    __shared__ alignas(16) unsigned char As[BM * BK];   // 16 KB
    __shared__ alignas(16) unsigned char Bs[BN * BK];   // 16 KB
    __shared__ float Es[BN];
    __shared__ unsigned int cU[BM][2];

    const int tid = threadIdx.x;
    const int lane = tid & 63;
    const int w = tid >> 6;
    const int ktile = blockIdx.x;
    const int mtile = blockIdx.y;
    const int mbase = mtile * BM;
    const int nbase = ktile * BN;

    if (tid < BN) Es[tid] = enorm[nbase + tid];

    f32x4 acc[16];
#pragma unroll
    for (int i = 0; i < 16; ++i) acc[i] = (f32x4){0.f, 0.f, 0.f, 0.f};

    const int rA = lane >> 3;                 // row within 8-row chunk
    const int jG = ((lane & 7) ^ rA) * 16;    // pre-swizzled global 16B chunk
    const int quad = lane >> 4;
    const int l15 = lane & 15;
    const int sw = l15 & 7;                   // read-side xor = row&7
    const int rw = (w >> 1) * 64;             // wave row quadrant
    const int cw = (w & 1) * 64;              // wave col quadrant
    // LDS slot s of row r holds global chunk s^(r&7). Lane needs global
    // chunks 2q, 2q+1 -> slots c0=(2q)^sw, c1=c0^1. Full sw spread: per
    // quad each b128 access covers 8 distinct chunks x 2 lanes = no
    // bank conflicts. lo/hi arrive in exact K order.
    const int o0 = ((quad << 1) ^ sw) * 16;
    const int o1 = o0 ^ 16;

    for (int dt = 0; dt < DIM; dt += BK) {
#pragma unroll
        for (int i = 0; i < 4; ++i) {
            int c = w * 4 + i;                // 1KB chunk id (0..15): rows c*8..c*8+7
            int row = c * 8 + rA;
            const unsigned char* ga = z8 + (size_t)(mbase + row) * DIM + dt + jG;
            const unsigned char* gb = cb8 + (size_t)(nbase + row) * DIM + dt + jG;
            unsigned char* la = As + c * 1024 + lane * 16;
            unsigned char* lb = Bs + c * 1024 + lane * 16;
            __builtin_amdgcn_global_load_lds((const __attribute__((address_space(1))) void*)ga,
                                             (__attribute__((address_space(3))) void*)la, 16, 0, 0);
            __builtin_amdgcn_global_load_lds((const __attribute__((address_space(1))) void*)gb,
                                             (__attribute__((address_space(3))) void*)lb, 16, 0, 0);
        }
        __syncthreads();
        i32x8 bfr[4];
#pragma unroll
        for (int cf = 0; cf < 4; ++cf) {
            const unsigned char* pb = Bs + (cw + cf * 16 + l15) * BK;
            int4 lo = *(const int4*)(pb + o0);
            int4 hi = *(const int4*)(pb + o1);
            bfr[cf] = (i32x8){lo.x, lo.y, lo.z, lo.w, hi.x, hi.y, hi.z, hi.w};
        }
#pragma unroll
        for (int rf = 0; rf < 4; ++rf) {
            const unsigned char* pa = As + (rw + rf * 16 + l15) * BK;
            int4 lo = *(const int4*)(pa + o0);
            int4 hi = *(const int4*)(pa + o1);
            i32x8 a = (i32x8){lo.x, lo.y, lo.z, lo.w, hi.x, hi.y, hi.z, hi.w};
#pragma unroll
            for (int cf = 0; cf < 4; ++cf)
                acc[rf * 4 + cf] = __builtin_amdgcn_mfma_scale_f32_16x16x128_f8f6f4(
                    a, bfr[cf], acc[rf * 4 + cf],
                    0, 0,                      // cbsz=fp8(e4m3), blgp=fp8(e4m3)
                    0, 0x7F7F7F7F,             // opsel_a, scale_a = 1.0 (e8m0 127)
                    0, 0x7F7F7F7F);            // opsel_b, scale_b = 1.0
        }
        __syncthreads();
    }

    // epilogue: per-row argmin over this tile's 128 cols.
    // C/D layout: col = lane&15, row = quad*4 + reg.
    // Packed key: monotone-uint(dist) with low 13 bits = global code index.
    float es[4];
#pragma unroll
    for (int cf = 0; cf < 4; ++cf) es[cf] = Es[cw + cf * 16 + l15];

#pragma unroll
    for (int rf = 0; rf < 4; ++rf) {
#pragma unroll
        for (int r = 0; r < 4; ++r) {
            float bv = 3.4e38f; int bi = 0;
#pragma unroll
            for (int cf = 0; cf < 4; ++cf) {
                int col = cw + cf * 16 + l15;
                float dist = fmaf(-2.0f, acc[rf * 4 + cf][r], es[cf]);
                if (dist < bv) { bv = dist; bi = col; }  // strict <: lowest col on tie
            }
            unsigned u = __builtin_bit_cast(unsigned, bv);
            u ^= ((unsigned)(((int)u) >> 31)) | 0x80000000u;
            unsigned key = (u & 0xFFFFE000u) | (unsigned)(nbase + bi);
#pragma unroll
            for (int m = 1; m < 16; m <<= 1) {
                unsigned o = __shfl_xor(key, m, 64);
                key = o < key ? o : key;
            }
            if (l15 == 0) cU[rw + rf * 16 + quad * 4 + r][w & 1] = key;
        }
    }
    __syncthreads();
    if (tid < BM) {
        unsigned k0 = cU[tid][0], k1 = cU[tid][1];
        // [ktile][row] layout: 128 consecutive ints per block = full-line writes
        candV[(size_t)ktile * M_ROWS + mbase + tid] = k0 < k1 ? k0 : k1;
    }
}

// ---- kernel 3: fused candidate-reduce + gather + ST output + loss ------
// 4 waves/block, each wave owns a row per iter: 64-lane umin over the 64
// packed candidates (lane = ktile) -> index, then 128 float4 slots.
__global__ __launch_bounds__(256) void gather_out(
    const float* __restrict__ z, const float* __restrict__ cb,
    const unsigned int* __restrict__ candV, float* __restrict__ out)
{
    __shared__ float red[4];
    const int tid = threadIdx.x;
    const int w = tid >> 6, lane = tid & 63;
    float lsum = 0.f;
#pragma unroll
    for (int it = 0; it < M_ROWS / (GB_BLOCKS * 4); ++it) {
        int row = (it * GB_BLOCKS + blockIdx.x) * 4 + w;
        unsigned key = candV[(size_t)lane * M_ROWS + row];
#pragma unroll
        for (int m = 1; m < 64; m <<= 1) {
            unsigned o = __shfl_xor(key, m, 64);
            key = o < key ? o : key;
        }
        int k = (int)(key & 8191u);
#pragma unroll
        for (int j = 0; j < 2; ++j) {
            int slot = lane + j * 64;
            float4 zv = ((const float4*)(z + (size_t)row * DIM))[slot];
            float4 cv = ((const float4*)(cb + (size_t)k * DIM))[slot];
            float dx = cv.x - zv.x, dy = cv.y - zv.y;
            float dz2 = cv.z - zv.z, dw = cv.w - zv.w;
            float4 o = {zv.x + dx, zv.y + dy, zv.z + dz2, zv.w + dw};  // z + sg(zq-z)
            ((float4*)(out + (size_t)row * DIM))[slot] = o;
            lsum += dx * dx + dy * dy + dz2 * dz2 + dw * dw;
        }
    }
    for (int m = 32; m; m >>= 1) lsum += __shfl_down(lsum, m, 64);
    if (lane == 0) red[w] = lsum;
    __syncthreads();
    if (tid == 0) {
        float t = (red[0] + red[1]) + (red[2] + red[3]);
        atomicAdd(out + OUT0_SIZE, t * (1.1f / (float)OUT0_SIZE));  // vq_loss = 1.1 * mean
    }
}

extern "C" void kernel_launch(void* const* d_in, const int* in_sizes, int n_in,
                              void* d_out, int out_size, void* d_ws, size_t ws_size,
                              hipStream_t stream) {
    const float* z = (const float*)d_in[0];     // 16*1024*512
    const float* cb = (const float*)d_in[1];    // 8192*512
    float* out = (float*)d_out;                 // 8388608 + 1
    char* ws = (char*)d_ws;

    // ws layout (bytes)
    unsigned char* z8   = (unsigned char*)(ws);               //  8,388,608
    unsigned char* cb8  = (unsigned char*)(ws + 8388608);     //  4,194,304
    float* enorm        = (float*)(ws + 12582912);            //     32,768
    unsigned int* candV = (unsigned int*)(ws + 12615680);     //  4,194,304

    convert_all<<<K_CODES / 4 + M_ROWS * DIM / 2048, 256, 0, stream>>>(
        z, cb, z8, cb8, enorm, out + OUT0_SIZE);
    gemm_argmin<<<dim3(NT, M_ROWS / BM), 256, 0, stream>>>(z8, cb8, enorm, candV);
    gather_out<<<GB_BLOCKS, 256, 0, stream>>>(z, cb, candV, out);
}

// Round 5
// 255.241 us; speedup vs baseline: 1.2299x; 1.0579x over previous
//
#include <hip/hip_runtime.h>

// VQ-VAE quantization: z [16384 x 512] f32, codebook [8192 x 512] f32.
// out = concat(z_st [16384*512] f32, vq_loss [1] f32).
//
// R4: MX-fp8 (e4m3, K=128 scaled MFMA) scores GEMM; packed (dist|idx) u32
// argmin epilogue. R6: spill fix + candV [ktile][row]. R7: (reverted R8)
// R8: - revert to R3 coarse-swizzle i32x8 fragment loads (A/B-faster; the
//       8.4M conflict counter is staging-invariant across all variants).
//     - XCD-locality remap: xcd=phys&7 owns mtile slice [xcd*16,xcd*16+16),
//       ktile advances every 128 blocks -> per-XCD working set = 1MB A
//       (L2-resident) + B-tile stream; L2-miss traffic ~1.07GB -> ~40MB.
//     - 2-phase dbuf pipeline: stage(dt+1) issued BEFORE compute(dt), one
//       barrier/iter -> fetch hides under MFMA (T3 minimum recipe).
//     - loss: per-block partials + tiny reduce kernel (was 1024
//       same-address device atomics = serialized tail).

#define M_ROWS 16384
#define K_CODES 8192
#define DIM 512
#define BM 128
#define BN 128
#define BK 128                 // fp8 bytes per K-step (one 16x16x128 MFMA)
#define NT (K_CODES / BN)      // 64 candidate tiles per row
#define OUT0_SIZE (M_ROWS * DIM)
#define GB_BLOCKS 1024

typedef int   i32x8 __attribute__((ext_vector_type(8)));
typedef float f32x4 __attribute__((ext_vector_type(4)));

template <bool HI>
__device__ __forceinline__ int pk8(float a, float b, int old) {
    return __builtin_amdgcn_cvt_pk_fp8_f32(a, b, old, HI);
}

// ---- kernel 1: fused converts ------------------------------------------
__global__ __launch_bounds__(256) void convert_all(
    const float* __restrict__ z, const float* __restrict__ cb,
    unsigned char* __restrict__ z8, unsigned char* __restrict__ cb8,
    float* __restrict__ enorm)
{
    const int tid = threadIdx.x;
    if (blockIdx.x < K_CODES / 4) {
        const int w = tid >> 6, lane = tid & 63;
        const int row = blockIdx.x * 4 + w;
        const float* src = cb + (size_t)row * DIM + lane * 8;
        float4 a = *(const float4*)(src);
        float4 b = *(const float4*)(src + 4);
        float ns = a.x * a.x + a.y * a.y + a.z * a.z + a.w * a.w
                 + b.x * b.x + b.y * b.y + b.z * b.z + b.w * b.w;
        const float S = 8192.0f;                 // exact power of 2
        int lo = 0, hi = 0;
        lo = pk8<false>(a.x * S, a.y * S, lo); lo = pk8<true>(a.z * S, a.w * S, lo);
        hi = pk8<false>(b.x * S, b.y * S, hi); hi = pk8<true>(b.z * S, b.w * S, hi);
        *(int2*)(cb8 + (size_t)row * DIM + lane * 8) = make_int2(lo, hi);
        for (int m = 32; m; m >>= 1) ns += __shfl_down(ns, m, 64);
        if (lane == 0) enorm[row] = S * ns;      // 8192 * ||e||^2 (f32-exact norm)
    } else {
        size_t i = ((size_t)(blockIdx.x - K_CODES / 4) * 256 + tid) * 8;
        float4 a = *(const float4*)(z + i);
        float4 b = *(const float4*)(z + i + 4);
        int lo = 0, hi = 0;
        lo = pk8<false>(a.x, a.y, lo); lo = pk8<true>(a.z, a.w, lo);
        hi = pk8<false>(b.x, b.y, hi); hi = pk8<true>(b.z, b.w, hi);
        *(int2*)(z8 + i) = make_int2(lo, hi);
    }
}

// ---- kernel 2: MX-fp8 MFMA GEMM + packed-argmin epilogue ---------------
__global__ __launch_bounds__(256, 2) void gemm_argmin(
    const unsigned char* __restrict__ z8, const unsigned char* __restrict__ cb8,
    const float* __restrict__ enorm, unsigned int* __restrict__ candV)
{
    __shared__ alignas(32) unsigned char As[2][BM * BK];   // 2 x 16 KB
    __shared__ alignas(32) unsigned char Bs[2][BN * BK];   // 2 x 16 KB
    __shared__ float Es[BN];
    __shared__ unsigned int cU[BM][2];

    const int tid = threadIdx.x;
    const int lane = tid & 63;
    const int w = tid >> 6;
    // XCD-locality remap: phys%8 = XCD (dispatch round-robin). Each XCD
    // owns mtiles [xcd*16, xcd*16+16) (1MB A-slice, L2-hot) and walks
    // ktiles slowly (16 same-XCD blocks share each 64KB B-tile).
    const int phys = blockIdx.x;
    const int xcd = phys & 7;
    const int idx = phys >> 3;
    const int ktile = idx >> 4;
    const int mtile = xcd * 16 + (idx & 15);
    const int mbase = mtile * BM;
    const int nbase = ktile * BN;

    if (tid < BN) Es[tid] = enorm[nbase + tid];

    f32x4 acc[16];
#pragma unroll
    for (int i = 0; i < 16; ++i) acc[i] = (f32x4){0.f, 0.f, 0.f, 0.f};

    const int rA = lane >> 3;                 // row within 8-row chunk
    const int jG = ((lane & 7) ^ rA) * 16;    // pre-swizzled global 16B chunk
    const int quad = lane >> 4;
    const int l15 = lane & 15;
    const int sw = l15 & 7;                   // read-side xor = row&7
    const int rw = (w >> 1) * 64;             // wave's row quadrant
    const int cw = (w & 1) * 64;              // wave's col quadrant
    // Chunks c0=(2q)^sw, c1=c0^1 form one aligned 32B block at
    // ((2q)^(sw&6))*16. Per-lane half-swap identical for A and B ->
    // per-lane dot product unchanged (R3-measured fastest variant).
    const int t32 = ((quad << 1) ^ (sw & 6)) * 16;

#define STAGE(buf, dt_) do {                                                  \
    _Pragma("unroll")                                                         \
    for (int i_ = 0; i_ < 4; ++i_) {                                          \
        int c_ = w * 4 + i_;                                                  \
        int row_ = c_ * 8 + rA;                                               \
        const unsigned char* ga_ = z8 + (size_t)(mbase + row_) * DIM + (dt_) * BK + jG; \
        const unsigned char* gb_ = cb8 + (size_t)(nbase + row_) * DIM + (dt_) * BK + jG; \
        unsigned char* la_ = As[buf] + c_ * 1024 + lane * 16;                 \
        unsigned char* lb_ = Bs[buf] + c_ * 1024 + lane * 16;                 \
        __builtin_amdgcn_global_load_lds((const __attribute__((address_space(1))) void*)ga_, \
                                         (__attribute__((address_space(3))) void*)la_, 16, 0, 0); \
        __builtin_amdgcn_global_load_lds((const __attribute__((address_space(1))) void*)gb_, \
                                         (__attribute__((address_space(3))) void*)lb_, 16, 0, 0); \
    } } while (0)

    STAGE(0, 0);
    __syncthreads();   // compiler drains vmcnt(0) before barrier -> buf0 ready

#pragma unroll
    for (int dt = 0; dt < 4; ++dt) {
        const int cur = dt & 1;
        if (dt < 3) STAGE(cur ^ 1, dt + 1);   // prefetch overlaps this compute
        i32x8 bfr[4];
#pragma unroll
        for (int cf = 0; cf < 4; ++cf)
            bfr[cf] = *(const i32x8*)(Bs[cur] + (cw + cf * 16 + l15) * BK + t32);
#pragma unroll
        for (int rf = 0; rf < 4; ++rf) {
            i32x8 a = *(const i32x8*)(As[cur] + (rw + rf * 16 + l15) * BK + t32);
#pragma unroll
            for (int cf = 0; cf < 4; ++cf)
                acc[rf * 4 + cf] = __builtin_amdgcn_mfma_scale_f32_16x16x128_f8f6f4(
                    a, bfr[cf], acc[rf * 4 + cf],
                    0, 0,                      // cbsz=fp8(e4m3), blgp=fp8(e4m3)
                    0, 0x7F7F7F7F,             // opsel_a, scale_a = 1.0 (e8m0 127)
                    0, 0x7F7F7F7F);            // opsel_b, scale_b = 1.0
        }
        __syncthreads();   // drains vmcnt(0): prefetched buffer landed; LDS reads done
    }
#undef STAGE

    // epilogue: per-row argmin over this tile's 128 cols.
    // C/D layout: col = lane&15, row = quad*4 + reg.
    // Packed key: monotone-uint(dist) with low 13 bits = global code index.
    float es[4];
#pragma unroll
    for (int cf = 0; cf < 4; ++cf) es[cf] = Es[cw + cf * 16 + l15];

#pragma unroll
    for (int rf = 0; rf < 4; ++rf) {
#pragma unroll
        for (int r = 0; r < 4; ++r) {
            float bv = 3.4e38f; int bi = 0;
#pragma unroll
            for (int cf = 0; cf < 4; ++cf) {
                int col = cw + cf * 16 + l15;
                float dist = fmaf(-2.0f, acc[rf * 4 + cf][r], es[cf]);
                if (dist < bv) { bv = dist; bi = col; }  // strict <: lowest col on tie
            }
            unsigned u = __builtin_bit_cast(unsigned, bv);
            u ^= ((unsigned)(((int)u) >> 31)) | 0x80000000u;
            unsigned key = (u & 0xFFFFE000u) | (unsigned)(nbase + bi);
#pragma unroll
            for (int m = 1; m < 16; m <<= 1) {
                unsigned o = __shfl_xor(key, m, 64);
                key = o < key ? o : key;
            }
            if (l15 == 0) cU[rw + rf * 16 + quad * 4 + r][w & 1] = key;
        }
    }
    __syncthreads();
    if (tid < BM) {
        unsigned k0 = cU[tid][0], k1 = cU[tid][1];
        // [ktile][row] layout: 128 consecutive ints per block = full-line writes
        candV[(size_t)ktile * M_ROWS + mbase + tid] = k0 < k1 ? k0 : k1;
    }
}

// ---- kernel 3: fused candidate-reduce + gather + ST output -------------
// 4 waves/block, each wave owns a row per iter: 64-lane umin over the 64
// packed candidates (lane = ktile) -> index, then 128 float4 slots.
// Loss partial per block -> plain store (atomic tail removed).
__global__ __launch_bounds__(256) void gather_out(
    const float* __restrict__ z, const float* __restrict__ cb,
    const unsigned int* __restrict__ candV, float* __restrict__ out,
    float* __restrict__ partials)
{
    __shared__ float red[4];
    const int tid = threadIdx.x;
    const int w = tid >> 6, lane = tid & 63;
    float lsum = 0.f;
#pragma unroll
    for (int it = 0; it < M_ROWS / (GB_BLOCKS * 4); ++it) {
        int row = (it * GB_BLOCKS + blockIdx.x) * 4 + w;
        unsigned key = candV[(size_t)lane * M_ROWS + row];
#pragma unroll
        for (int m = 1; m < 64; m <<= 1) {
            unsigned o = __shfl_xor(key, m, 64);
            key = o < key ? o : key;
        }
        int k = (int)(key & 8191u);
#pragma unroll
        for (int j = 0; j < 2; ++j) {
            int slot = lane + j * 64;
            float4 zv = ((const float4*)(z + (size_t)row * DIM))[slot];
            float4 cv = ((const float4*)(cb + (size_t)k * DIM))[slot];
            float dx = cv.x - zv.x, dy = cv.y - zv.y;
            float dz2 = cv.z - zv.z, dw = cv.w - zv.w;
            float4 o = {zv.x + dx, zv.y + dy, zv.z + dz2, zv.w + dw};  // z + sg(zq-z)
            ((float4*)(out + (size_t)row * DIM))[slot] = o;
            lsum += dx * dx + dy * dy + dz2 * dz2 + dw * dw;
        }
    }
    for (int m = 32; m; m >>= 1) lsum += __shfl_down(lsum, m, 64);
    if (lane == 0) red[w] = lsum;
    __syncthreads();
    if (tid == 0) partials[blockIdx.x] = (red[0] + red[1]) + (red[2] + red[3]);
}

// ---- kernel 4: final loss reduction (1024 partials -> scalar) ----------
__global__ __launch_bounds__(256) void reduce_loss(
    const float* __restrict__ partials, float* __restrict__ lossOut)
{
    __shared__ float red[4];
    const int tid = threadIdx.x;
    float s = 0.f;
#pragma unroll
    for (int i = 0; i < GB_BLOCKS / 256; ++i) s += partials[i * 256 + tid];
    for (int m = 32; m; m >>= 1) s += __shfl_down(s, m, 64);
    if ((tid & 63) == 0) red[tid >> 6] = s;
    __syncthreads();
    if (tid == 0)
        lossOut[0] = ((red[0] + red[1]) + (red[2] + red[3])) * (1.1f / (float)OUT0_SIZE);
}

extern "C" void kernel_launch(void* const* d_in, const int* in_sizes, int n_in,
                              void* d_out, int out_size, void* d_ws, size_t ws_size,
                              hipStream_t stream) {
    const float* z = (const float*)d_in[0];     // 16*1024*512
    const float* cb = (const float*)d_in[1];    // 8192*512
    float* out = (float*)d_out;                 // 8388608 + 1
    char* ws = (char*)d_ws;

    // ws layout (bytes)
    unsigned char* z8   = (unsigned char*)(ws);               //  8,388,608
    unsigned char* cb8  = (unsigned char*)(ws + 8388608);     //  4,194,304
    float* enorm        = (float*)(ws + 12582912);            //     32,768
    unsigned int* candV = (unsigned int*)(ws + 12615680);     //  4,194,304
    float* partials     = (float*)(ws + 16809984);            //      4,096

    convert_all<<<K_CODES / 4 + M_ROWS * DIM / 2048, 256, 0, stream>>>(
        z, cb, z8, cb8, enorm);
    gemm_argmin<<<NT * (M_ROWS / BM), 256, 0, stream>>>(z8, cb8, enorm, candV);
    gather_out<<<GB_BLOCKS, 256, 0, stream>>>(z, cb, candV, out, partials);
    reduce_loss<<<1, 256, 0, stream>>>(partials, out + OUT0_SIZE);
}